// Round 3
// baseline (250.086 us; speedup 1.0000x reference)
//
#include <hip/hip_runtime.h>

#define NN 4096
#define BB 64
#define KK 128
#define EE 256

typedef unsigned short u16;
typedef __bf16 bhalf;
typedef bhalf bhalf8 __attribute__((ext_vector_type(8)));
typedef float floatx4 __attribute__((ext_vector_type(4)));

__device__ __forceinline__ float b2f(u16 u) {
  union { unsigned int i; float f; } v; v.i = ((unsigned int)u) << 16; return v.f;
}
__device__ __forceinline__ u16 f2b(float f) {
  union { float f; unsigned int i; } v; v.f = f;
  unsigned int r = (v.i + 0x7FFFu + ((v.i >> 16) & 1u)) >> 16;
  return (u16)r;
}
__device__ __forceinline__ float silu_f(float v) {
  return v / (1.f + __expf(-v));
}

// ---- f32 -> bf16 cast ----
__global__ __launch_bounds__(256) void cast_k(const float* __restrict__ in,
                                              u16* __restrict__ o, int n) {
  int i = blockIdx.x * 256 + threadIdx.x;
  if (i < n) o[i] = f2b(in[i]);
}

// ---- segment boundaries: seg[b] = lower_bound(batch_seg, b), seg[64] = N ----
__global__ void seg_k(const int* __restrict__ bs, int* __restrict__ seg) {
  int b = threadIdx.x;
  if (b <= BB) {
    int lo = 0, hi = NN;
    while (lo < hi) { int mid = (lo + hi) >> 1; if (bs[mid] < b) lo = mid + 1; else hi = mid; }
    seg[b] = lo;
  }
}

// ---- Y = silu(X @ W^T) [+ skip], bf16 in, f32 accum via MFMA ----
// wave computes 16(m) x 64(n); block = 2 waves -> 32 x 64 tile
// Output: bf16 to Y (if Yf==null) else f32 to Yf.
__global__ __launch_bounds__(128) void gemm_k(
    const u16* __restrict__ X, const u16* __restrict__ W,
    u16* __restrict__ Y, const u16* __restrict__ skip, float* __restrict__ Yf)
{
  const int lane = threadIdx.x & 63;
  const int wv = threadIdx.x >> 6;
  const int m0 = (blockIdx.x * 2 + wv) * 16;
  const int n0 = blockIdx.y * 64;
  const int r = lane & 15, q = lane >> 4;
  const u16* Ap = X + (m0 + r) * EE + q * 8;
  const u16* Bp = W + (n0 + r) * EE + q * 8;
  floatx4 acc[4];
#pragma unroll
  for (int t = 0; t < 4; ++t) acc[t] = (floatx4){0.f, 0.f, 0.f, 0.f};
#pragma unroll
  for (int k0 = 0; k0 < EE; k0 += 32) {
    bhalf8 av = *(const bhalf8*)(Ap + k0);
#pragma unroll
    for (int t = 0; t < 4; ++t) {
      bhalf8 bv = *(const bhalf8*)(Bp + t * 16 * EE + k0);
      acc[t] = __builtin_amdgcn_mfma_f32_16x16x32_bf16(av, bv, acc[t], 0, 0, 0);
    }
  }
#pragma unroll
  for (int t = 0; t < 4; ++t) {
    int col = n0 + t * 16 + r;
#pragma unroll
    for (int i = 0; i < 4; ++i) {
      int row = m0 + q * 4 + i;
      float v = silu_f(acc[t][i]);
      if (skip) v += b2f(skip[row * EE + col]);
      if (Yf) Yf[row * EE + col] = v;
      else    Y[row * EE + col] = f2b(v);
    }
  }
}

// ---- dot[n,kk] = k[bs[n],kk,:] . x[n,:]; f32 dot out + f32 cos/sin ----
__global__ __launch_bounds__(256) void dot_k(
    const float* __restrict__ x, const float* __restrict__ kvec, const int* __restrict__ bs,
    float* __restrict__ dout, float* __restrict__ cw, float* __restrict__ sw)
{
  int tid = blockIdx.x * 256 + threadIdx.x;   // = n*KK + kk
  int n = tid >> 7;
  int kk = tid & (KK - 1);
  int b = bs[n];
  const float* kp = kvec + (b * KK + kk) * 3;
  const float* xp = x + n * 3;
  float d = kp[0] * xp[0] + kp[1] * xp[1] + kp[2] * xp[2];
  float sv, cv;
  sincosf(d, &sv, &cv);
  dout[tid] = d;
  cw[tid] = cv;
  sw[tid] = sv;
}

// ---- kfilter[kk,e] = sum_d W_up[e,d] * W_down[d,kk]  (f32) ----
__global__ __launch_bounds__(256) void kf_k(
    const float* __restrict__ Wup, const float* __restrict__ Wdn, float* __restrict__ kf)
{
  int kk = blockIdx.x, e = threadIdx.x;
  float a = 0.f;
#pragma unroll
  for (int d = 0; d < 8; ++d) a += Wup[e * 8 + d] * Wdn[d * KK + kk];
  kf[kk * EE + e] = a;
}

// ---- filtered structure factors: Fr/Fi[b,kk,e] = kf[kk,e] * sum_n c/s[n,kk]*hres[n,e] ----
// block = (b, kk-tile of 8), threads = e
__global__ __launch_bounds__(256) void sf_k(
    const u16* __restrict__ hres, const float* __restrict__ cw, const float* __restrict__ sw,
    const float* __restrict__ kf, const int* __restrict__ seg,
    float* __restrict__ Fr, float* __restrict__ Fi)
{
  int b = blockIdx.x, kk0 = blockIdx.y * 8, e = threadIdx.x;
  int n0 = seg[b], n1 = seg[b + 1];
  float ar[8], ai[8];
#pragma unroll
  for (int j = 0; j < 8; ++j) { ar[j] = 0.f; ai[j] = 0.f; }
  for (int n = n0; n < n1; ++n) {
    float h = b2f(hres[n * EE + e]);
    floatx4 c0 = *(const floatx4*)(cw + n * KK + kk0);
    floatx4 c1 = *(const floatx4*)(cw + n * KK + kk0 + 4);
    floatx4 s0 = *(const floatx4*)(sw + n * KK + kk0);
    floatx4 s1 = *(const floatx4*)(sw + n * KK + kk0 + 4);
#pragma unroll
    for (int j = 0; j < 4; ++j) {
      ar[j]     += c0[j] * h;
      ar[4 + j] += c1[j] * h;
      ai[j]     += s0[j] * h;
      ai[4 + j] += s1[j] * h;
    }
  }
#pragma unroll
  for (int j = 0; j < 8; ++j) {
    float f = kf[(kk0 + j) * EE + e];
    Fr[(b * KK + kk0 + j) * EE + e] = ar[j] * f;
    Fi[(b * KK + kk0 + j) * EE + e] = ai[j] * f;
  }
}

// ---- h_update[n,e] = 0.01 * sum_kk (c[n,kk]*Fr[b,kk,e] + s[n,kk]*Fi[b,kk,e]) ----
// block = (b, e-tile of 32); LDS-stage Fr/Fi tile; threads = (kq 0..7) x (el 0..31)
__global__ __launch_bounds__(256) void hupd_k(
    const float* __restrict__ Fr, const float* __restrict__ Fi,
    const float* __restrict__ cw, const float* __restrict__ sw,
    const int* __restrict__ seg, u16* __restrict__ hupd)
{
  const int b = blockIdx.x, e0 = blockIdx.y * 32;
  const int t = threadIdx.x, el = t & 31, kq = t >> 5;
  __shared__ float FL[KK][32][2];
  __shared__ float part[8][32];
  for (int i = t; i < KK * 32; i += 256) {
    int kk = i >> 5, e = i & 31;
    FL[kk][e][0] = Fr[(b * KK + kk) * EE + e0 + e];
    FL[kk][e][1] = Fi[(b * KK + kk) * EE + e0 + e];
  }
  __syncthreads();
  int n0 = seg[b], n1 = seg[b + 1];
  for (int n = n0; n < n1; ++n) {
    const float* cp = cw + n * KK + kq * 16;
    const float* sp = sw + n * KK + kq * 16;
    floatx4 c0 = *(const floatx4*)(cp);
    floatx4 c1 = *(const floatx4*)(cp + 4);
    floatx4 c2 = *(const floatx4*)(cp + 8);
    floatx4 c3 = *(const floatx4*)(cp + 12);
    floatx4 s0 = *(const floatx4*)(sp);
    floatx4 s1 = *(const floatx4*)(sp + 4);
    floatx4 s2 = *(const floatx4*)(sp + 8);
    floatx4 s3 = *(const floatx4*)(sp + 12);
    float acc = 0.f;
#pragma unroll
    for (int j = 0; j < 4; ++j) {
      int kb = kq * 16;
      acc += c0[j] * FL[kb + j][el][0]      + s0[j] * FL[kb + j][el][1];
      acc += c1[j] * FL[kb + 4 + j][el][0]  + s1[j] * FL[kb + 4 + j][el][1];
      acc += c2[j] * FL[kb + 8 + j][el][0]  + s2[j] * FL[kb + 8 + j][el][1];
      acc += c3[j] * FL[kb + 12 + j][el][0] + s3[j] * FL[kb + 12 + j][el][1];
    }
    part[kq][el] = acc;
    __syncthreads();
    if (t < 32) {
      float ssum = 0.f;
#pragma unroll
      for (int q2 = 0; q2 < 8; ++q2) ssum += part[q2][t];
      hupd[n * EE + e0 + t] = f2b(0.01f * ssum);
    }
    __syncthreads();
  }
}

extern "C" void kernel_launch(void* const* d_in, const int* in_sizes, int n_in,
                              void* d_out, int out_size, void* d_ws, size_t ws_size,
                              hipStream_t stream) {
  const float* h    = (const float*)d_in[0];
  const float* x    = (const float*)d_in[1];
  const float* kv   = (const float*)d_in[2];
  const int*   bs   = (const int*)d_in[3];
  const float* Wpre = (const float*)d_in[5];
  const float* Wdn  = (const float*)d_in[6];
  const float* Wup  = (const float*)d_in[7];
  const float* W0   = (const float*)d_in[8];
  const float* Wres = (const float*)d_in[9];
  float* out = (float*)d_out;          // [0, N*E) = hu, [N*E, N*E+N*K) = dot

  // f32 workspace
  float* cw = (float*)d_ws;                 // N*K
  float* sw = cw + NN * KK;                 // N*K
  float* kf = sw + NN * KK;                 // K*E
  float* Fr = kf + KK * EE;                 // B*K*E
  float* Fi = Fr + BB * KK * EE;            // B*K*E
  int* seg  = (int*)(Fi + BB * KK * EE);    // 65 (padded 128)
  // bf16 workspace
  u16* hb   = (u16*)(seg + 128);            // N*E
  u16* wpre = hb + NN * EE;                 // 2*E*E
  u16* w0b  = wpre + 2 * EE * EE;           // E*E
  u16* wrb  = w0b + EE * EE;                // 6*E*E
  u16* t1   = wrb + 6 * EE * EE;            // N*E
  u16* t2   = t1 + NN * EE;
  u16* t3   = t2 + NN * EE;
  u16* hupd = t3 + NN * EE;
  u16* hres = t3;

  dim3 gg(NN / 32, EE / 64);

  seg_k<<<1, 128, 0, stream>>>(bs, seg);
  cast_k<<<(NN * EE + 255) / 256, 256, 0, stream>>>(h, hb, NN * EE);
  cast_k<<<(2 * EE * EE + 255) / 256, 256, 0, stream>>>(Wpre, wpre, 2 * EE * EE);
  cast_k<<<(EE * EE + 255) / 256, 256, 0, stream>>>(W0, w0b, EE * EE);
  cast_k<<<(6 * EE * EE + 255) / 256, 256, 0, stream>>>(Wres, wrb, 6 * EE * EE);

  // pre-residual: t1 = silu(hb@Wp0^T); hres = hb + silu(t1@Wp1^T)
  gemm_k<<<gg, 128, 0, stream>>>(hb, wpre, t1, nullptr, nullptr);
  gemm_k<<<gg, 128, 0, stream>>>(t1, wpre + EE * EE, hres, hb, nullptr);
  // dot + cos/sin (dot -> Output 1 region, f32)
  dot_k<<<NN * KK / 256, 256, 0, stream>>>(x, kv, bs, out + NN * EE, cw, sw);
  kf_k<<<KK, EE, 0, stream>>>(Wup, Wdn, kf);
  sf_k<<<dim3(BB, KK / 8), 256, 0, stream>>>(hres, cw, sw, kf, seg, Fr, Fi);
  hupd_k<<<dim3(BB, EE / 32), 256, 0, stream>>>(Fr, Fi, cw, sw, seg, hupd);
  // update MLP: t1 = silu(hupd@W0^T), then 3 residual blocks
  gemm_k<<<gg, 128, 0, stream>>>(hupd, w0b, t1, nullptr, nullptr);
  gemm_k<<<gg, 128, 0, stream>>>(t1, wrb + 0 * EE * EE, t2, nullptr, nullptr);
  gemm_k<<<gg, 128, 0, stream>>>(t2, wrb + 1 * EE * EE, t3, t1, nullptr);
  gemm_k<<<gg, 128, 0, stream>>>(t3, wrb + 2 * EE * EE, t2, nullptr, nullptr);
  gemm_k<<<gg, 128, 0, stream>>>(t2, wrb + 3 * EE * EE, t1, t3, nullptr);
  gemm_k<<<gg, 128, 0, stream>>>(t1, wrb + 4 * EE * EE, t2, nullptr, nullptr);
  // final: hu (f32) into out[0:N*E], skip-add t1
  gemm_k<<<gg, 128, 0, stream>>>(t2, wrb + 5 * EE * EE, nullptr, t1, out);
}

// Round 4
// 188.268 us; speedup vs baseline: 1.3284x; 1.3284x over previous
//
#include <hip/hip_runtime.h>

#define NN 4096
#define BB 64
#define KK 128
#define EE 256
#define HTS 4224   // ht row stride (NN + 128 slack)
#define PCAP 160   // per-structure padded atom capacity (abase-relative)

typedef unsigned short u16;
typedef __bf16 bhalf;
typedef bhalf bhalf8 __attribute__((ext_vector_type(8)));
typedef float floatx4 __attribute__((ext_vector_type(4)));

__device__ __forceinline__ float b2f(u16 u) {
  union { unsigned int i; float f; } v; v.i = ((unsigned int)u) << 16; return v.f;
}
__device__ __forceinline__ u16 f2b(float f) {
  union { float f; unsigned int i; } v; v.f = f;
  unsigned int r = (v.i + 0x7FFFu + ((v.i >> 16) & 1u)) >> 16;
  return (u16)r;
}
__device__ __forceinline__ float silu_f(float v) {
  return v / (1.f + __expf(-v));
}

// ---- fused prep: weight/h casts, kft, csb slack zero, seg ----
__global__ __launch_bounds__(256) void prep_k(
    const float* __restrict__ h, const float* __restrict__ Wpre,
    const float* __restrict__ W0, const float* __restrict__ Wres,
    const float* __restrict__ Wup, const float* __restrict__ Wdn,
    const int* __restrict__ bs,
    u16* __restrict__ hb, u16* __restrict__ wpre, u16* __restrict__ w0b,
    u16* __restrict__ wrb, float* __restrict__ kft, u16* __restrict__ csb,
    int* __restrict__ seg)
{
  int bid = blockIdx.x, tid = threadIdx.x;
  if (bid < 4096)      { int i = bid * 256 + tid;          hb[i]   = f2b(h[i]); }
  else if (bid < 4608) { int i = (bid - 4096) * 256 + tid; wpre[i] = f2b(Wpre[i]); }
  else if (bid < 4864) { int i = (bid - 4608) * 256 + tid; w0b[i]  = f2b(W0[i]); }
  else if (bid < 6400) { int i = (bid - 4864) * 256 + tid; wrb[i]  = f2b(Wres[i]); }
  else if (bid < 6528) {
    int i = (bid - 6400) * 256 + tid;     // kft[e][kk]
    int e = i >> 7, kk = i & 127;
    float a = 0.f;
#pragma unroll
    for (int d = 0; d < 8; ++d) a += Wup[e * 8 + d] * Wdn[d * KK + kk];
    kft[i] = a;
  } else if (bid < 6656) {
    int i = (bid - 6528) * 256 + tid;     // zero csb rows [4096, 4224)
    csb[4096 * 256 + i] = 0;
  } else {
    int b = tid;
    if (b <= BB) {
      int lo = 0, hi = NN;
      while (lo < hi) { int mid = (lo + hi) >> 1; if (bs[mid] < b) lo = mid + 1; else hi = mid; }
      seg[b] = lo;
    }
  }
}

// ---- n-major dot: dout f32, csb[n][0:128]=cos, [128:256]=sin (bf16) ----
__global__ __launch_bounds__(256) void dot_n_k(
    const float* __restrict__ x, const float* __restrict__ kvec, const int* __restrict__ bs,
    float* __restrict__ dout, u16* __restrict__ csb)
{
  int tid = blockIdx.x * 256 + threadIdx.x;   // n*128 + kk
  int n = tid >> 7, kk = tid & 127;
  int b = bs[n];
  const float* kp = kvec + (b * KK + kk) * 3;
  const float* xp = x + n * 3;
  float d = kp[0] * xp[0] + kp[1] * xp[1] + kp[2] * xp[2];
  float sv, cv;
  sincosf(d, &sv, &cv);
  dout[tid] = d;
  csb[(n << 8) + kk] = f2b(cv);
  csb[(n << 8) + 128 + kk] = f2b(sv);
}

// ---- transposed dot: ctb[b][j][p] (j<128: cos, j>=128: sin), zero-padded ----
__global__ __launch_bounds__(192) void dot_t_k(
    const float* __restrict__ x, const float* __restrict__ kvec,
    const int* __restrict__ seg, u16* __restrict__ ctb)
{
  int b = blockIdx.x, j = blockIdx.y, p = threadIdx.x;
  if (p >= PCAP) return;
  int s0 = seg[b], s1 = seg[b + 1];
  int abase = s0 & ~7;
  int plo = s0 - abase, phi = s1 - abase;
  float val = 0.f;
  if (p >= plo && p < phi) {
    int n = abase + p;
    int kk = j & 127;
    const float* kp = kvec + (b * KK + kk) * 3;
    const float* xp = x + n * 3;
    float d = kp[0] * xp[0] + kp[1] * xp[1] + kp[2] * xp[2];
    val = (j < KK) ? cosf(d) : sinf(d);
  }
  ctb[((b << 8) + j) * PCAP + p] = f2b(val);
}

// ---- Y = silu(X @ W^T) [+ skip bf16], wave = 32m x 64n, block 2 waves ----
__global__ __launch_bounds__(128) void gemm_k(
    const u16* __restrict__ X, const u16* __restrict__ W,
    u16* __restrict__ Y, const u16* __restrict__ skip, float* __restrict__ Yf)
{
  const int lane = threadIdx.x & 63;
  const int wv = threadIdx.x >> 6;
  const int m0 = blockIdx.x * 64 + wv * 32;
  const int n0 = blockIdx.y * 64;
  const int r = lane & 15, q = lane >> 4;
  const u16* Ap = X + (m0 + r) * EE + q * 8;
  const u16* Bp = W + (n0 + r) * EE + q * 8;
  floatx4 acc[2][4];
#pragma unroll
  for (int m = 0; m < 2; ++m)
#pragma unroll
    for (int t = 0; t < 4; ++t) acc[m][t] = (floatx4){0.f, 0.f, 0.f, 0.f};
#pragma unroll
  for (int k0 = 0; k0 < EE; k0 += 32) {
    bhalf8 a0 = *(const bhalf8*)(Ap + k0);
    bhalf8 a1 = *(const bhalf8*)(Ap + 16 * EE + k0);
#pragma unroll
    for (int t = 0; t < 4; ++t) {
      bhalf8 bv = *(const bhalf8*)(Bp + t * 16 * EE + k0);
      acc[0][t] = __builtin_amdgcn_mfma_f32_16x16x32_bf16(a0, bv, acc[0][t], 0, 0, 0);
      acc[1][t] = __builtin_amdgcn_mfma_f32_16x16x32_bf16(a1, bv, acc[1][t], 0, 0, 0);
    }
  }
#pragma unroll
  for (int m = 0; m < 2; ++m)
#pragma unroll
    for (int t = 0; t < 4; ++t) {
      int col = n0 + t * 16 + r;
#pragma unroll
      for (int i = 0; i < 4; ++i) {
        int row = m0 + m * 16 + q * 4 + i;
        float v = silu_f(acc[m][t][i]);
        if (skip) v += b2f(skip[row * EE + col]);
        if (Yf) Yf[row * EE + col] = v;
        else    Y[row * EE + col] = f2b(v);
      }
    }
}

// ---- transposed 2nd pre-residual: ht[e][n] = h[n][e] + silu(Wpre1[e][:] . t1[n][:]) ----
__global__ __launch_bounds__(128) void gemm2t_k(
    const u16* __restrict__ W2, const u16* __restrict__ T1,
    const float* __restrict__ h, u16* __restrict__ ht)
{
  const int lane = threadIdx.x & 63;
  const int wv = threadIdx.x >> 6;
  const int m0 = blockIdx.x * 64 + wv * 32;   // e
  const int n0 = blockIdx.y * 64;             // n
  const int r = lane & 15, q = lane >> 4;
  const u16* Ap = W2 + (m0 + r) * EE + q * 8;
  const u16* Bp = T1 + (n0 + r) * EE + q * 8;
  floatx4 acc[2][4];
#pragma unroll
  for (int m = 0; m < 2; ++m)
#pragma unroll
    for (int t = 0; t < 4; ++t) acc[m][t] = (floatx4){0.f, 0.f, 0.f, 0.f};
#pragma unroll
  for (int k0 = 0; k0 < EE; k0 += 32) {
    bhalf8 a0 = *(const bhalf8*)(Ap + k0);
    bhalf8 a1 = *(const bhalf8*)(Ap + 16 * EE + k0);
#pragma unroll
    for (int t = 0; t < 4; ++t) {
      bhalf8 bv = *(const bhalf8*)(Bp + t * 16 * EE + k0);
      acc[0][t] = __builtin_amdgcn_mfma_f32_16x16x32_bf16(a0, bv, acc[0][t], 0, 0, 0);
      acc[1][t] = __builtin_amdgcn_mfma_f32_16x16x32_bf16(a1, bv, acc[1][t], 0, 0, 0);
    }
  }
#pragma unroll
  for (int m = 0; m < 2; ++m)
#pragma unroll
    for (int t = 0; t < 4; ++t) {
      int col = n0 + t * 16 + r;              // n
#pragma unroll
      for (int i = 0; i < 4; ++i) {
        int row = m0 + m * 16 + q * 4 + i;    // e
        float v = silu_f(acc[m][t][i]) + h[col * EE + row];
        ht[row * HTS + col] = f2b(v);
      }
    }
}

// ---- sf GEMM: F[b][e][j] = kft[e][j&127] * sum_p ht[e][abase+p] * ctb[b][j][p] ----
__global__ __launch_bounds__(256) void sf_k(
    const u16* __restrict__ ht, const u16* __restrict__ ctb,
    const float* __restrict__ kft, const int* __restrict__ seg, u16* __restrict__ F)
{
  const int lane = threadIdx.x & 63;
  const int wv = threadIdx.x >> 6;
  const int b = blockIdx.x;
  const int e0 = blockIdx.y * 128 + wv * 32;
  const int j0 = blockIdx.z * 64;
  const int r = lane & 15, q = lane >> 4;
  const int abase = seg[b] & ~7;
  const int phi = seg[b + 1] - abase;         // <= 135 < PCAP
  const u16* Ap = ht + (e0 + r) * HTS + abase + q * 8;
  const u16* Bp = ctb + ((b << 8) + j0 + r) * PCAP + q * 8;
  floatx4 acc[2][4];
#pragma unroll
  for (int m = 0; m < 2; ++m)
#pragma unroll
    for (int t = 0; t < 4; ++t) acc[m][t] = (floatx4){0.f, 0.f, 0.f, 0.f};
  for (int p0 = 0; p0 < phi; p0 += 32) {
    bhalf8 a0 = *(const bhalf8*)(Ap + p0);
    bhalf8 a1 = *(const bhalf8*)(Ap + 16 * HTS + p0);
#pragma unroll
    for (int t = 0; t < 4; ++t) {
      bhalf8 bv = *(const bhalf8*)(Bp + t * 16 * PCAP + p0);
      acc[0][t] = __builtin_amdgcn_mfma_f32_16x16x32_bf16(a0, bv, acc[0][t], 0, 0, 0);
      acc[1][t] = __builtin_amdgcn_mfma_f32_16x16x32_bf16(a1, bv, acc[1][t], 0, 0, 0);
    }
  }
#pragma unroll
  for (int m = 0; m < 2; ++m)
#pragma unroll
    for (int t = 0; t < 4; ++t) {
      int col = j0 + t * 16 + r;
      int kk = col & 127;
#pragma unroll
      for (int i = 0; i < 4; ++i) {
        int row = e0 + m * 16 + q * 4 + i;    // e
        F[((b << 8) + row) * 256 + col] = f2b(acc[m][t][i] * kft[row * KK + kk]);
      }
    }
}

// ---- hupd GEMM: U[n][e] = 0.01 * sum_j csb[n][j] * F[b][e][j] ----
__global__ __launch_bounds__(256) void hupd_k(
    const u16* __restrict__ csb, const u16* __restrict__ F,
    const int* __restrict__ seg, u16* __restrict__ hupd)
{
  const int lane = threadIdx.x & 63;
  const int wv = threadIdx.x >> 6;
  const int b = blockIdx.x;
  const int m0L = blockIdx.y * 64 + (wv >> 1) * 32;
  const int e0  = blockIdx.z * 128 + (wv & 1) * 64;
  const int r = lane & 15, q = lane >> 4;
  const int n0s = seg[b];
  const int len = seg[b + 1] - n0s;
  if (m0L >= len) return;
  const u16* Ap = csb + (n0s + m0L + r) * 256 + q * 8;
  const u16* Bp = F + ((b << 8) + e0 + r) * 256 + q * 8;
  floatx4 acc[2][4];
#pragma unroll
  for (int m = 0; m < 2; ++m)
#pragma unroll
    for (int t = 0; t < 4; ++t) acc[m][t] = (floatx4){0.f, 0.f, 0.f, 0.f};
#pragma unroll
  for (int j0 = 0; j0 < 256; j0 += 32) {
    bhalf8 a0 = *(const bhalf8*)(Ap + j0);
    bhalf8 a1 = *(const bhalf8*)(Ap + 16 * 256 + j0);
#pragma unroll
    for (int t = 0; t < 4; ++t) {
      bhalf8 bv = *(const bhalf8*)(Bp + t * 16 * 256 + j0);
      acc[0][t] = __builtin_amdgcn_mfma_f32_16x16x32_bf16(a0, bv, acc[0][t], 0, 0, 0);
      acc[1][t] = __builtin_amdgcn_mfma_f32_16x16x32_bf16(a1, bv, acc[1][t], 0, 0, 0);
    }
  }
#pragma unroll
  for (int m = 0; m < 2; ++m)
#pragma unroll
    for (int t = 0; t < 4; ++t) {
      int e = e0 + t * 16 + r;
#pragma unroll
      for (int i = 0; i < 4; ++i) {
        int rowL = m0L + m * 16 + q * 4 + i;
        if (rowL < len) hupd[(n0s + rowL) * EE + e] = f2b(0.01f * acc[m][t][i]);
      }
    }
}

extern "C" void kernel_launch(void* const* d_in, const int* in_sizes, int n_in,
                              void* d_out, int out_size, void* d_ws, size_t ws_size,
                              hipStream_t stream) {
  const float* h    = (const float*)d_in[0];
  const float* x    = (const float*)d_in[1];
  const float* kv   = (const float*)d_in[2];
  const int*   bs   = (const int*)d_in[3];
  const float* Wpre = (const float*)d_in[5];
  const float* Wdn  = (const float*)d_in[6];
  const float* Wup  = (const float*)d_in[7];
  const float* W0   = (const float*)d_in[8];
  const float* Wres = (const float*)d_in[9];
  float* out = (float*)d_out;          // [0, N*E) = hu, [N*E, ..) = dot

  float* kft = (float*)d_ws;                  // 256*128
  int*   seg = (int*)(kft + EE * KK);         // 128
  u16* hb   = (u16*)(seg + 128);              // N*E
  u16* wpre = hb + NN * EE;                   // 2*E*E
  u16* w0b  = wpre + 2 * EE * EE;             // E*E
  u16* wrb  = w0b + EE * EE;                  // 6*E*E
  u16* csb  = wrb + 6 * EE * EE;              // 4224*256 (slack rows zeroed)
  u16* ctb  = csb + HTS * 256;                // B*256*PCAP
  u16* ht   = ctb + BB * 256 * PCAP;          // 256*HTS
  u16* F    = ht + 256 * HTS;                 // B*256*256
  u16* t1   = F + BB * 256 * 256;             // N*E
  u16* t2   = t1 + NN * EE;
  u16* t3   = t2 + NN * EE;
  u16* hupd = t3 + NN * EE;

  dim3 gg(NN / 64, EE / 64);

  prep_k<<<6657, 256, 0, stream>>>(h, Wpre, W0, Wres, Wup, Wdn, bs,
                                   hb, wpre, w0b, wrb, kft, csb, seg);
  dot_n_k<<<NN * KK / 256, 256, 0, stream>>>(x, kv, bs, out + NN * EE, csb);
  dot_t_k<<<dim3(BB, 256), 192, 0, stream>>>(x, kv, seg, ctb);
  // pre-residual
  gemm_k<<<gg, 128, 0, stream>>>(hb, wpre, t1, nullptr, nullptr);
  gemm2t_k<<<dim3(EE / 64, NN / 64), 128, 0, stream>>>(wpre + EE * EE, t1, h, ht);
  // structure factors + filter (MFMA), back-projection (MFMA)
  sf_k<<<dim3(BB, 2, 4), 256, 0, stream>>>(ht, ctb, kft, seg, F);
  hupd_k<<<dim3(BB, 2, 2), 256, 0, stream>>>(csb, F, seg, hupd);
  // update MLP
  gemm_k<<<gg, 128, 0, stream>>>(hupd, w0b, t1, nullptr, nullptr);
  gemm_k<<<gg, 128, 0, stream>>>(t1, wrb + 0 * EE * EE, t2, nullptr, nullptr);
  gemm_k<<<gg, 128, 0, stream>>>(t2, wrb + 1 * EE * EE, t3, t1, nullptr);
  gemm_k<<<gg, 128, 0, stream>>>(t3, wrb + 2 * EE * EE, t2, nullptr, nullptr);
  gemm_k<<<gg, 128, 0, stream>>>(t2, wrb + 3 * EE * EE, t1, t3, nullptr);
  gemm_k<<<gg, 128, 0, stream>>>(t1, wrb + 4 * EE * EE, t2, nullptr, nullptr);
  gemm_k<<<gg, 128, 0, stream>>>(t2, wrb + 5 * EE * EE, nullptr, t1, out);
}

// Round 5
// 171.079 us; speedup vs baseline: 1.4618x; 1.1005x over previous
//
#include <hip/hip_runtime.h>

#define NN 4096
#define BB 64
#define KK 128
#define EE 256
#define HTS 4352   // ht row stride (NN + 256 slack; sf_k K-loop may read to +191)
#define CSR 4224   // csb rows (NN + 128 slack, zeroed)
#define PCAP 160   // per-structure padded atom capacity (abase-relative)
#define YTS 264    // pair_k LDS y row stride (u16)
#define ZTS 20     // pair_k LDS zt row stride (u16)

typedef unsigned short u16;
typedef __bf16 bhalf;
typedef bhalf bhalf8 __attribute__((ext_vector_type(8)));
typedef float floatx4 __attribute__((ext_vector_type(4)));

__device__ __forceinline__ float b2f(u16 u) {
  union { unsigned int i; float f; } v; v.i = ((unsigned int)u) << 16; return v.f;
}
__device__ __forceinline__ u16 f2b(float f) {
  union { float f; unsigned int i; } v; v.f = f;
  unsigned int r = (v.i + 0x7FFFu + ((v.i >> 16) & 1u)) >> 16;
  return (u16)r;
}
__device__ __forceinline__ float silu_f(float v) {
  return v / (1.f + __expf(-v));
}

// ---- fused prep: weight/h casts, kft, csb slack zero, seg ----
__global__ __launch_bounds__(256) void prep_k(
    const float* __restrict__ h, const float* __restrict__ Wpre,
    const float* __restrict__ W0, const float* __restrict__ Wres,
    const float* __restrict__ Wup, const float* __restrict__ Wdn,
    const int* __restrict__ bs,
    u16* __restrict__ hb, u16* __restrict__ wpre, u16* __restrict__ w0b,
    u16* __restrict__ wrb, float* __restrict__ kft, u16* __restrict__ csb,
    int* __restrict__ seg)
{
  int bid = blockIdx.x, tid = threadIdx.x;
  if (bid < 4096)      { int i = bid * 256 + tid;          hb[i]   = f2b(h[i]); }
  else if (bid < 4608) { int i = (bid - 4096) * 256 + tid; wpre[i] = f2b(Wpre[i]); }
  else if (bid < 4864) { int i = (bid - 4608) * 256 + tid; w0b[i]  = f2b(W0[i]); }
  else if (bid < 6400) { int i = (bid - 4864) * 256 + tid; wrb[i]  = f2b(Wres[i]); }
  else if (bid < 6528) {
    int i = (bid - 6400) * 256 + tid;     // kft[e][kk]
    int e = i >> 7, kk = i & 127;
    float a = 0.f;
#pragma unroll
    for (int d = 0; d < 8; ++d) a += Wup[e * 8 + d] * Wdn[d * KK + kk];
    kft[i] = a;
  } else if (bid < 6528 + 128) {
    int i = (bid - 6528) * 256 + tid;     // zero csb rows [4096, 4224)
    csb[4096 * 256 + i] = 0;
  } else {
    int b = tid;
    if (b <= BB) {
      int lo = 0, hi = NN;
      while (lo < hi) { int mid = (lo + hi) >> 1; if (bs[mid] < b) lo = mid + 1; else hi = mid; }
      seg[b] = lo;
    }
  }
}

// ---- n-major dot: dout f32, csb[n][0:128]=cos, [128:256]=sin (bf16) ----
__global__ __launch_bounds__(256) void dot_n_k(
    const float* __restrict__ x, const float* __restrict__ kvec, const int* __restrict__ bs,
    float* __restrict__ dout, u16* __restrict__ csb)
{
  int tid = blockIdx.x * 256 + threadIdx.x;   // n*128 + kk
  int n = tid >> 7, kk = tid & 127;
  int b = bs[n];
  const float* kp = kvec + (b * KK + kk) * 3;
  const float* xp = x + n * 3;
  float d = kp[0] * xp[0] + kp[1] * xp[1] + kp[2] * xp[2];
  float sv, cv;
  sincosf(d, &sv, &cv);
  dout[tid] = d;
  csb[(n << 8) + kk] = f2b(cv);
  csb[(n << 8) + 128 + kk] = f2b(sv);
}

// ---- ctb[b][j][p] = csb[abase+p][j] (zero outside segment) — LDS transpose ----
__global__ __launch_bounds__(256) void trans_k(
    const u16* __restrict__ csb, const int* __restrict__ seg, u16* __restrict__ ctb)
{
  __shared__ u16 ld[32 * 258];
  int b = blockIdx.x, p0 = blockIdx.y * 32, t = threadIdx.x;
  int s0 = seg[b], s1 = seg[b + 1];
  int abase = s0 & ~7;
#pragma unroll
  for (int it = 0; it < 32; ++it) {
    int idx = it * 256 + t;
    int pl = idx >> 8, j = idx & 255;
    int n = abase + p0 + pl;
    u16 v = 0;
    if (n >= s0 && n < s1) v = csb[(n << 8) | j];
    ld[pl * 258 + j] = v;
  }
  __syncthreads();
  unsigned w[16];
#pragma unroll
  for (int i = 0; i < 16; ++i) {
    unsigned lo = ld[(2 * i) * 258 + t];
    unsigned hi = ld[(2 * i + 1) * 258 + t];
    w[i] = lo | (hi << 16);
  }
  uint4* dst = (uint4*)(ctb + ((b << 8) + t) * PCAP + p0);
#pragma unroll
  for (int i = 0; i < 4; ++i) {
    uint4 u; u.x = w[4*i]; u.y = w[4*i+1]; u.z = w[4*i+2]; u.w = w[4*i+3];
    dst[i] = u;
  }
}

// ---- fused pair: out = skip + silu(silu(X@Wa^T)@Wb^T) ----
// block = 4 waves, 16 rows x full 256 cols; y kept in LDS.
// Yt!=null: write transposed to Yt[e][n] with f32 hskip. Else skip=X; Yf f32 or Yb bf16.
__global__ __launch_bounds__(256) void pair_k(
    const u16* __restrict__ X, const u16* __restrict__ Wa, const u16* __restrict__ Wb,
    u16* __restrict__ Yb, float* __restrict__ Yf,
    u16* __restrict__ Yt, const float* __restrict__ hskip)
{
  __shared__ u16 lds[5120];   // y: 16 x YTS(264) = 4224; zt: 256 x ZTS(20) = 5120
  const int lane = threadIdx.x & 63, wv = threadIdx.x >> 6;
  const int m0 = blockIdx.x * 16;
  const int n0 = wv * 64;
  const int r = lane & 15, q = lane >> 4;
  const u16* Ap = X + (m0 + r) * EE + q * 8;
  const u16* Bp = Wa + (n0 + r) * EE + q * 8;
  floatx4 acc[4];
#pragma unroll
  for (int t = 0; t < 4; ++t) acc[t] = (floatx4){0.f, 0.f, 0.f, 0.f};
#pragma unroll
  for (int k0 = 0; k0 < EE; k0 += 32) {
    bhalf8 av = *(const bhalf8*)(Ap + k0);
#pragma unroll
    for (int t = 0; t < 4; ++t) {
      bhalf8 bv = *(const bhalf8*)(Bp + t * 16 * EE + k0);
      acc[t] = __builtin_amdgcn_mfma_f32_16x16x32_bf16(av, bv, acc[t], 0, 0, 0);
    }
  }
#pragma unroll
  for (int t = 0; t < 4; ++t) {
    int col = n0 + t * 16 + r;
#pragma unroll
    for (int i = 0; i < 4; ++i)
      lds[(q * 4 + i) * YTS + col] = f2b(silu_f(acc[t][i]));
  }
  __syncthreads();
  const u16* Bp2 = Wb + (n0 + r) * EE + q * 8;
#pragma unroll
  for (int t = 0; t < 4; ++t) acc[t] = (floatx4){0.f, 0.f, 0.f, 0.f};
#pragma unroll
  for (int k0 = 0; k0 < EE; k0 += 32) {
    bhalf8 av = *(const bhalf8*)(&lds[r * YTS + q * 8 + k0]);
#pragma unroll
    for (int t = 0; t < 4; ++t) {
      bhalf8 bv = *(const bhalf8*)(Bp2 + t * 16 * EE + k0);
      acc[t] = __builtin_amdgcn_mfma_f32_16x16x32_bf16(av, bv, acc[t], 0, 0, 0);
    }
  }
  if (!Yt) {
#pragma unroll
    for (int t = 0; t < 4; ++t) {
      int col = n0 + t * 16 + r;
#pragma unroll
      for (int i = 0; i < 4; ++i) {
        int g = m0 + q * 4 + i;
        float v = silu_f(acc[t][i]) + b2f(X[g * EE + col]);
        if (Yf) Yf[g * EE + col] = v;
        else    Yb[g * EE + col] = f2b(v);
      }
    }
  } else {
    __syncthreads();   // all y-reads done before overwriting lds as zt
#pragma unroll
    for (int t = 0; t < 4; ++t) {
      int col = n0 + t * 16 + r;
#pragma unroll
      for (int i = 0; i < 4; ++i) {
        int g = m0 + q * 4 + i;
        float v = silu_f(acc[t][i]) + hskip[g * EE + col];
        lds[col * ZTS + q * 4 + i] = f2b(v);
      }
    }
    __syncthreads();
    int e = threadIdx.x;
    const uint2* src = (const uint2*)&lds[e * ZTS];
    uint2* dst = (uint2*)(Yt + e * HTS + m0);
#pragma unroll
    for (int i = 0; i < 4; ++i) dst[i] = src[i];
  }
}

// ---- single GEMM: Y = silu(X @ W^T), wave = 32m x 64n, block 2 waves ----
__global__ __launch_bounds__(128) void gemm_k(
    const u16* __restrict__ X, const u16* __restrict__ W, u16* __restrict__ Y)
{
  const int lane = threadIdx.x & 63;
  const int wv = threadIdx.x >> 6;
  const int m0 = blockIdx.x * 64 + wv * 32;
  const int n0 = blockIdx.y * 64;
  const int r = lane & 15, q = lane >> 4;
  const u16* Ap = X + (m0 + r) * EE + q * 8;
  const u16* Bp = W + (n0 + r) * EE + q * 8;
  floatx4 acc[2][4];
#pragma unroll
  for (int m = 0; m < 2; ++m)
#pragma unroll
    for (int t = 0; t < 4; ++t) acc[m][t] = (floatx4){0.f, 0.f, 0.f, 0.f};
#pragma unroll
  for (int k0 = 0; k0 < EE; k0 += 32) {
    bhalf8 a0 = *(const bhalf8*)(Ap + k0);
    bhalf8 a1 = *(const bhalf8*)(Ap + 16 * EE + k0);
#pragma unroll
    for (int t = 0; t < 4; ++t) {
      bhalf8 bv = *(const bhalf8*)(Bp + t * 16 * EE + k0);
      acc[0][t] = __builtin_amdgcn_mfma_f32_16x16x32_bf16(a0, bv, acc[0][t], 0, 0, 0);
      acc[1][t] = __builtin_amdgcn_mfma_f32_16x16x32_bf16(a1, bv, acc[1][t], 0, 0, 0);
    }
  }
#pragma unroll
  for (int m = 0; m < 2; ++m)
#pragma unroll
    for (int t = 0; t < 4; ++t) {
      int col = n0 + t * 16 + r;
#pragma unroll
      for (int i = 0; i < 4; ++i) {
        int row = m0 + m * 16 + q * 4 + i;
        Y[row * EE + col] = f2b(silu_f(acc[m][t][i]));
      }
    }
}

// ---- sf GEMM: F[b][e][j] = kft[e][j&127] * sum_p ht[e][abase+p] * ctb[b][j][p] ----
__global__ __launch_bounds__(256) void sf_k(
    const u16* __restrict__ ht, const u16* __restrict__ ctb,
    const float* __restrict__ kft, const int* __restrict__ seg, u16* __restrict__ F)
{
  const int lane = threadIdx.x & 63;
  const int wv = threadIdx.x >> 6;
  const int b = blockIdx.x;
  const int e0 = blockIdx.y * 128 + wv * 32;
  const int j0 = blockIdx.z * 64;
  const int r = lane & 15, q = lane >> 4;
  const int abase = seg[b] & ~7;
  const int phi = seg[b + 1] - abase;         // <= 135 < PCAP
  const u16* Ap = ht + (e0 + r) * HTS + abase + q * 8;
  const u16* Bp = ctb + ((b << 8) + j0 + r) * PCAP + q * 8;
  floatx4 acc[2][4];
#pragma unroll
  for (int m = 0; m < 2; ++m)
#pragma unroll
    for (int t = 0; t < 4; ++t) acc[m][t] = (floatx4){0.f, 0.f, 0.f, 0.f};
  for (int p0 = 0; p0 < phi; p0 += 32) {
    bhalf8 a0 = *(const bhalf8*)(Ap + p0);
    bhalf8 a1 = *(const bhalf8*)(Ap + 16 * HTS + p0);
#pragma unroll
    for (int t = 0; t < 4; ++t) {
      bhalf8 bv = *(const bhalf8*)(Bp + t * 16 * PCAP + p0);
      acc[0][t] = __builtin_amdgcn_mfma_f32_16x16x32_bf16(a0, bv, acc[0][t], 0, 0, 0);
      acc[1][t] = __builtin_amdgcn_mfma_f32_16x16x32_bf16(a1, bv, acc[1][t], 0, 0, 0);
    }
  }
#pragma unroll
  for (int m = 0; m < 2; ++m)
#pragma unroll
    for (int t = 0; t < 4; ++t) {
      int col = j0 + t * 16 + r;
      int kk = col & 127;
#pragma unroll
      for (int i = 0; i < 4; ++i) {
        int row = e0 + m * 16 + q * 4 + i;    // e
        F[((b << 8) + row) * 256 + col] = f2b(acc[m][t][i] * kft[row * KK + kk]);
      }
    }
}

// ---- hupd GEMM: U[n][e] = 0.01 * sum_j csb[n][j] * F[b][e][j] ----
__global__ __launch_bounds__(256) void hupd_k(
    const u16* __restrict__ csb, const u16* __restrict__ F,
    const int* __restrict__ seg, u16* __restrict__ hupd)
{
  const int lane = threadIdx.x & 63;
  const int wv = threadIdx.x >> 6;
  const int b = blockIdx.x;
  const int m0L = blockIdx.y * 64 + (wv >> 1) * 32;
  const int e0  = blockIdx.z * 128 + (wv & 1) * 64;
  const int r = lane & 15, q = lane >> 4;
  const int n0s = seg[b];
  const int len = seg[b + 1] - n0s;
  if (m0L >= len) return;
  const u16* Ap = csb + (n0s + m0L + r) * 256 + q * 8;
  const u16* Bp = F + ((b << 8) + e0 + r) * 256 + q * 8;
  floatx4 acc[2][4];
#pragma unroll
  for (int m = 0; m < 2; ++m)
#pragma unroll
    for (int t = 0; t < 4; ++t) acc[m][t] = (floatx4){0.f, 0.f, 0.f, 0.f};
#pragma unroll
  for (int j0 = 0; j0 < 256; j0 += 32) {
    bhalf8 a0 = *(const bhalf8*)(Ap + j0);
    bhalf8 a1 = *(const bhalf8*)(Ap + 16 * 256 + j0);
#pragma unroll
    for (int t = 0; t < 4; ++t) {
      bhalf8 bv = *(const bhalf8*)(Bp + t * 16 * 256 + j0);
      acc[0][t] = __builtin_amdgcn_mfma_f32_16x16x32_bf16(a0, bv, acc[0][t], 0, 0, 0);
      acc[1][t] = __builtin_amdgcn_mfma_f32_16x16x32_bf16(a1, bv, acc[1][t], 0, 0, 0);
    }
  }
#pragma unroll
  for (int m = 0; m < 2; ++m)
#pragma unroll
    for (int t = 0; t < 4; ++t) {
      int e = e0 + t * 16 + r;
#pragma unroll
      for (int i = 0; i < 4; ++i) {
        int rowL = m0L + m * 16 + q * 4 + i;
        if (rowL < len) hupd[(n0s + rowL) * EE + e] = f2b(0.01f * acc[m][t][i]);
      }
    }
}

extern "C" void kernel_launch(void* const* d_in, const int* in_sizes, int n_in,
                              void* d_out, int out_size, void* d_ws, size_t ws_size,
                              hipStream_t stream) {
  const float* h    = (const float*)d_in[0];
  const float* x    = (const float*)d_in[1];
  const float* kv   = (const float*)d_in[2];
  const int*   bs   = (const int*)d_in[3];
  const float* Wpre = (const float*)d_in[5];
  const float* Wdn  = (const float*)d_in[6];
  const float* Wup  = (const float*)d_in[7];
  const float* W0   = (const float*)d_in[8];
  const float* Wres = (const float*)d_in[9];
  float* out = (float*)d_out;          // [0, N*E) = hu, [N*E, ..) = dot

  float* kft = (float*)d_ws;                  // 256*128
  int*   seg = (int*)(kft + EE * KK);         // 128
  u16* hb   = (u16*)(seg + 128);              // N*E
  u16* wpre = hb + NN * EE;                   // 2*E*E
  u16* w0b  = wpre + 2 * EE * EE;             // E*E
  u16* wrb  = w0b + EE * EE;                  // 6*E*E
  u16* csb  = wrb + 6 * EE * EE;              // CSR*256 (slack rows zeroed)
  u16* ctb  = csb + CSR * 256;                // B*256*PCAP
  u16* ht   = ctb + BB * 256 * PCAP;          // 256*HTS
  u16* F    = ht + 256 * HTS;                 // B*256*256
  u16* t1   = F + BB * 256 * 256;             // N*E
  u16* hupd = t1 + NN * EE;                   // N*E

  prep_k<<<6657, 256, 0, stream>>>(h, Wpre, W0, Wres, Wup, Wdn, bs,
                                   hb, wpre, w0b, wrb, kft, csb, seg);
  dot_n_k<<<NN * KK / 256, 256, 0, stream>>>(x, kv, bs, out + NN * EE, csb);
  trans_k<<<dim3(BB, PCAP / 32), 256, 0, stream>>>(csb, seg, ctb);
  // fused pre-residual -> ht (transposed, +h skip)
  pair_k<<<NN / 16, 256, 0, stream>>>(hb, wpre, wpre + EE * EE,
                                      nullptr, nullptr, ht, h);
  // structure factors + filter (MFMA), back-projection (MFMA)
  sf_k<<<dim3(BB, 2, 4), 256, 0, stream>>>(ht, ctb, kft, seg, F);
  hupd_k<<<dim3(BB, 2, 2), 256, 0, stream>>>(csb, F, seg, hupd);
  // update MLP: t1 = silu(hupd@W0^T); then 3 fused residual pairs
  gemm_k<<<dim3(NN / 64, EE / 64), 128, 0, stream>>>(hupd, w0b, t1);
  pair_k<<<NN / 16, 256, 0, stream>>>(t1, wrb + 0 * EE * EE, wrb + 1 * EE * EE,
                                      t1, nullptr, nullptr, nullptr);
  pair_k<<<NN / 16, 256, 0, stream>>>(t1, wrb + 2 * EE * EE, wrb + 3 * EE * EE,
                                      t1, nullptr, nullptr, nullptr);
  pair_k<<<NN / 16, 256, 0, stream>>>(t1, wrb + 4 * EE * EE, wrb + 5 * EE * EE,
                                      nullptr, out, nullptr, nullptr);
}